// Round 5
// baseline (209.934 us; speedup 1.0000x reference)
//
#include <hip/hip_runtime.h>
#include <cmath>

#define B_ 16
#define N_ 48
#define HID_ 64
#define NL_ 128
#define NNODE_ (B_*N_)        // 768
#define NEDGE_ (B_*N_*N_)     // 36864

__device__ __forceinline__ float sigmoidf_(float x){ return 1.0f/(1.0f+expf(-x)); }

// ---------------------------------------------------------------------------
// K_PM: fat kernel. Blocks [0,576): edge-MLP relu2. Blocks [576,961): prep
// (A/B column sums, bias sums, h_first, mask, GRU weight transposes).
// mlp layer-2 reads w1 directly (register transpose) -> no prep dependency.
// ---------------------------------------------------------------------------
__global__ __launch_bounds__(256) void k_pm(
    const float* __restrict__ ein, const float* __restrict__ w0, const float* __restrict__ b0,
    const float* __restrict__ w1, const float* __restrict__ b1,
    const float* __restrict__ w2, const float* __restrict__ b2,
    const float* __restrict__ h0,
    const float* __restrict__ wih, const float* __restrict__ whh,
    float* __restrict__ relu2,
    float* __restrict__ A, float* __restrict__ Bm,
    float* __restrict__ Ab, float* __restrict__ Bb,
    float* __restrict__ hfirst, float* __restrict__ mask,
    float* __restrict__ wihT, float* __restrict__ whhT)
{
    __shared__ __align__(16) float x1s[64*132];
    int tid = threadIdx.x;

    if (blockIdx.x < 576){
        // ================= edge MLP =================
        int et = tid & 15, ot = tid >> 4;
        int o0 = ot * 8;
        size_t e0 = (size_t)blockIdx.x * 64;

        // ---- layer 1 ----
        float acc[4][8];
        {
            float4 ba = *(const float4*)&b0[o0];
            float4 bb = *(const float4*)&b0[o0 + 4];
            #pragma unroll
            for (int q = 0; q < 4; q++){
                acc[q][0]=ba.x; acc[q][1]=ba.y; acc[q][2]=ba.z; acc[q][3]=ba.w;
                acc[q][4]=bb.x; acc[q][5]=bb.y; acc[q][6]=bb.z; acc[q][7]=bb.w;
            }
        }
        #pragma unroll
        for (int i4 = 0; i4 < 4; i4++){
            float4 ev[4];
            #pragma unroll
            for (int q = 0; q < 4; q++)
                ev[q] = *(const float4*)&ein[(e0 + q*16 + et)*16 + i4*4];
            float wr[4][8];
            #pragma unroll
            for (int d = 0; d < 4; d++){
                *(float4*)&wr[d][0] = *(const float4*)&w0[(i4*4+d)*128 + o0];
                *(float4*)&wr[d][4] = *(const float4*)&w0[(i4*4+d)*128 + o0 + 4];
            }
            #pragma unroll
            for (int q = 0; q < 4; q++){
                #pragma unroll
                for (int r2 = 0; r2 < 8; r2++)
                    acc[q][r2] += ev[q].x*wr[0][r2] + ev[q].y*wr[1][r2]
                                + ev[q].z*wr[2][r2] + ev[q].w*wr[3][r2];
            }
        }
        #pragma unroll
        for (int q = 0; q < 4; q++){
            int e = q*16 + et;
            float4 s0 = make_float4(fmaxf(acc[q][0],0.f), fmaxf(acc[q][1],0.f),
                                    fmaxf(acc[q][2],0.f), fmaxf(acc[q][3],0.f));
            float4 s1 = make_float4(fmaxf(acc[q][4],0.f), fmaxf(acc[q][5],0.f),
                                    fmaxf(acc[q][6],0.f), fmaxf(acc[q][7],0.f));
            *(float4*)&x1s[e*132 + o0]     = s0;
            *(float4*)&x1s[e*132 + o0 + 4] = s1;
        }
        __syncthreads();

        // ---- layer 2 ----
        float a2[4][8];
        {
            float4 ba = *(const float4*)&b1[o0];
            float4 bb = *(const float4*)&b1[o0 + 4];
            #pragma unroll
            for (int q = 0; q < 4; q++){
                a2[q][0]=ba.x; a2[q][1]=ba.y; a2[q][2]=ba.z; a2[q][3]=ba.w;
                a2[q][4]=bb.x; a2[q][5]=bb.y; a2[q][6]=bb.z; a2[q][7]=bb.w;
            }
        }
        for (int i4 = 0; i4 < 32; i4++){
            int i = i4*4;
            float wr[4][8];
            #pragma unroll
            for (int d = 0; d < 4; d++){
                *(float4*)&wr[d][0] = *(const float4*)&w1[(size_t)(i+d)*128 + o0];
                *(float4*)&wr[d][4] = *(const float4*)&w1[(size_t)(i+d)*128 + o0 + 4];
            }
            #pragma unroll
            for (int q = 0; q < 4; q++){
                float4 xv = *(const float4*)&x1s[(q*16 + et)*132 + i];
                #pragma unroll
                for (int r2 = 0; r2 < 8; r2++)
                    a2[q][r2] += xv.x*wr[0][r2] + xv.y*wr[1][r2]
                               + xv.z*wr[2][r2] + xv.w*wr[3][r2];
            }
        }
        #pragma unroll
        for (int q = 0; q < 4; q++){
            size_t e = e0 + q*16 + et;
            float4 s0 = make_float4(fmaxf(a2[q][0],0.f), fmaxf(a2[q][1],0.f),
                                    fmaxf(a2[q][2],0.f), fmaxf(a2[q][3],0.f));
            float4 s1 = make_float4(fmaxf(a2[q][4],0.f), fmaxf(a2[q][5],0.f),
                                    fmaxf(a2[q][6],0.f), fmaxf(a2[q][7],0.f));
            *(float4*)&relu2[e*128 + o0]     = s0;
            *(float4*)&relu2[e*128 + o0 + 4] = s1;
        }
    } else {
        // ================= prep =================
        int idx = (blockIdx.x - 576)*256 + tid;
        if (idx < 24576) {
            int r = idx >> 13, c = (idx >> 6) & 127, m = idx & 63;
            int t = 48 - 16*r;                  // 48/32/16, multiple of 16
            const float* src = w2 + c*4096 + m*64;
            float a = 0.f, b = 0.f;
            #pragma unroll
            for (int k4 = 0; k4 < 16; k4++){
                float4 v = *(const float4*)&src[k4*4];
                float s = v.x + v.y + v.z + v.w;
                if (k4*4 < t) a += s; else b += s;
            }
            A[idx] = a; Bm[idx] = b;
        } else if (idx < 24768) {
            int i2 = idx - 24576;
            int r = i2 >> 6, m = i2 & 63;
            int t = 48 - 16*r;
            const float* src = b2 + m*64;
            float a = 0.f, b = 0.f;
            #pragma unroll
            for (int k4 = 0; k4 < 16; k4++){
                float4 v = *(const float4*)&src[k4*4];
                float s = v.x + v.y + v.z + v.w;
                if (k4*4 < t) a += s; else b += s;
            }
            Ab[i2] = a; Bb[i2] = b;
        } else if (idx < 73920) {
            int i3 = idx - 24768;
            int node = i3 >> 6, m = i3 & 63;
            hfirst[i3] = (m < 32) ? h0[node*32 + m] : 0.f;
            if (m == 0) {
                float s = 0.f;
                #pragma unroll
                for (int k = 0; k < 32; k++) s += h0[node*32 + k];
                mask[node] = (s > 0.f) ? 1.f : 0.f;
            }
        } else if (idx < 98496) {
            int i4 = idx - 73920;
            if (i4 < 12288) {
                int k = i4 / 192, col = i4 - k*192;
                wihT[i4] = wih[col*64 + k];
            } else {
                int i5 = i4 - 12288;
                int k = i5 / 192, col = i5 - k*192;
                whhT[i5] = whh[col*64 + k];
            }
        }
    }
}

// ---------------------------------------------------------------------------
// K3: one message-passing layer + GRU. Block per (b,j), 256 threads, 6 phases.
// P1 stages relu2 tile (24KB) + h + g*h + Ab/Bb into LDS and shuffle-reduces
// sA/sB; P2 U/V from LDS; P3 agg (pU combine inlined); P4 aggs; P5 GRU; P6 out.
// ---------------------------------------------------------------------------
__global__ __launch_bounds__(256) void k_layer(
    const float* __restrict__ hin, float* __restrict__ hout,
    const float* __restrict__ relu2,
    const float* __restrict__ A, const float* __restrict__ Bm,
    const float* __restrict__ Ab, const float* __restrict__ Bb,
    const float* __restrict__ g, const float* __restrict__ mask,
    const float* __restrict__ wihT, const float* __restrict__ whhT,
    const float* __restrict__ bih, const float* __restrict__ bhh)
{
    int bj = blockIdx.x;
    int b = bj / 48, j = bj - b*48;
    int r = j % 3;
    int p0 = j + j/3;
    int tid = threadIdx.x;
    int base = b*48;
    __shared__ __align__(16) float r2s[48*128];   // 24 KB
    __shared__ float hs[64], wAs[64], wBs[64], Abs[64], Bbs[64];
    __shared__ float pU[2][128], pV[2][128];
    __shared__ float pC[4][64];
    __shared__ float aggs[64], gi[192], gh[192];
    __shared__ float sAB[2];

    // ---- P1: issue all independent loads ----
    {
        const float* src = relu2 + ((size_t)base*48 + j)*128;   // row i at +i*6144
        #pragma unroll
        for (int q2 = 0; q2 < 6; q2++){
            int flat = q2*256 + tid;               // float4 index, 0..1535
            int row = flat >> 5, col = (flat & 31)*4;
            float4 v = *(const float4*)&src[(size_t)row*6144 + col];
            *(float4*)&r2s[row*128 + col] = v;
        }
    }
    if (tid < 64){
        hs[tid] = hin[(size_t)bj*64 + tid];
    } else if (tid < 128){
        int i = tid - 64;                          // lane i of wave 1
        float wa = 0.f, wb = 0.f;
        if (i < 48){
            float gv = g[(size_t)(base+i)*48 + j];
            wa = gv * hin[(size_t)(base+i)*64 + p0];
            wb = gv * hin[(size_t)(base+i)*64 + p0 + 1];
        }
        wAs[i] = wa; wBs[i] = wb;
        float sa = wa, sb = wb;
        #pragma unroll
        for (int d = 32; d >= 1; d >>= 1){
            sa += __shfl_xor(sa, d, 64);
            sb += __shfl_xor(sb, d, 64);
        }
        if (i == 0){ sAB[0] = sa; sAB[1] = sb; }
    } else if (tid < 192){
        Bbs[tid-128] = Bb[r*64 + (tid-128)];
    } else {
        Abs[tid-192] = Ab[r*64 + (tid-192)];
    }
    __syncthreads();

    // ---- P2: U/V partials (all from LDS, conflict-free) ----
    {
        int c = tid & 127, half = tid >> 7;
        float aU = 0.f, aV = 0.f;
        #pragma unroll
        for (int ii = 0; ii < 24; ii++){
            int i = half*24 + ii;
            float v = r2s[i*128 + c];
            aU += wAs[i]*v; aV += wBs[i]*v;
        }
        pU[half][c] = aU; pV[half][c] = aV;
    }
    __syncthreads();

    // ---- P3: agg partials over c (pU combine inlined; A/B streamed) ----
    {
        int m = tid & 63, cg = tid >> 6;
        const float* Arp = A  + r*8192 + m;
        const float* Brp = Bm + r*8192 + m;
        float a = 0.f;
        #pragma unroll
        for (int cc = 0; cc < 32; cc++){
            int c = cg*32 + cc;
            float u = pU[0][c] + pU[1][c];
            float v = pV[0][c] + pV[1][c];
            a += u*Arp[(size_t)c*64] + v*Brp[(size_t)c*64];
        }
        pC[cg][m] = a;
    }
    __syncthreads();

    // ---- P4: combine aggs + bias-sum terms ----
    if (tid < 64){
        aggs[tid] = pC[0][tid] + pC[1][tid] + pC[2][tid] + pC[3][tid]
                  + sAB[0]*Abs[tid] + sAB[1]*Bbs[tid];
    }
    __syncthreads();

    // ---- P5: GRU gate matvecs ----
    if (tid < 192){
        float gacc = bih[tid], hacc = bhh[tid];
        #pragma unroll 16
        for (int k = 0; k < 64; k++){
            gacc += aggs[k] * wihT[k*192 + tid];
            hacc += hs[k]   * whhT[k*192 + tid];
        }
        gi[tid] = gacc; gh[tid] = hacc;
    }
    __syncthreads();

    // ---- P6: GRU nonlinearity + masked write ----
    if (tid < 64){
        float rr = sigmoidf_(gi[tid] + gh[tid]);
        float zz = sigmoidf_(gi[64+tid] + gh[64+tid]);
        float nn = tanhf(gi[128+tid] + rr*gh[128+tid]);
        float hnew = (1.f - zz)*nn + zz*hs[tid];
        hout[(size_t)bj*64 + tid] = mask[bj] * hnew;
    }
}

// ---------------------------------------------------------------------------
// K4: readout, 192 blocks (16 batches x 12 groups of 4 nodes), 256 threads.
// ---------------------------------------------------------------------------
__device__ __forceinline__ void rd_layer(
    const float* __restrict__ Xs, const float* __restrict__ W,
    const float* __restrict__ bias, float* __restrict__ Ys,
    int dim, int o, int ng, bool do_relu)
{
    float a0 = bias[o];
    float a1 = a0;
    #pragma unroll 8
    for (int i = 0; i < dim; i += 4){
        float w0 = W[(size_t)(i+0)*128 + o];
        float w1 = W[(size_t)(i+1)*128 + o];
        float w2 = W[(size_t)(i+2)*128 + o];
        float w3 = W[(size_t)(i+3)*128 + o];
        const float4 x0 = *(const float4*)&Xs[ng*128 + i];
        const float4 x1 = *(const float4*)&Xs[(ng+2)*128 + i];
        a0 += x0.x*w0 + x0.y*w1 + x0.z*w2 + x0.w*w3;
        a1 += x1.x*w0 + x1.y*w1 + x1.z*w2 + x1.w*w3;
    }
    if (do_relu){ a0 = fmaxf(a0, 0.f); a1 = fmaxf(a1, 0.f); }
    Ys[ng*128 + o] = a0;
    Ys[(ng+2)*128 + o] = a1;
}

__global__ __launch_bounds__(256) void k_read(
    const float* __restrict__ hfirst, const float* __restrict__ hT,
    const float* __restrict__ mask,
    const float* __restrict__ w00, const float* __restrict__ b00,
    const float* __restrict__ w01, const float* __restrict__ b01,
    const float* __restrict__ w02, const float* __restrict__ b02,
    const float* __restrict__ w10, const float* __restrict__ b10,
    const float* __restrict__ w11, const float* __restrict__ b11,
    const float* __restrict__ w12, const float* __restrict__ b12,
    float* __restrict__ partial)
{
    __shared__ __align__(16) float xs[4*128];
    __shared__ __align__(16) float ys[4*128];
    __shared__ __align__(16) float zs[4*128];
    __shared__ __align__(16) float os0[4*128];
    __shared__ float mS[4];
    int tid = threadIdx.x;
    int b = blockIdx.x / 12, gg = blockIdx.x - b*12;
    int node0 = b*48 + gg*4;
    int o = tid & 127, ng = tid >> 7;
    if (tid < 4) mS[tid] = mask[node0 + tid];
    for (int i = tid; i < 4*128; i += 256){
        int r = i >> 7, c = i & 127;
        xs[i] = (c < 64) ? hfirst[(size_t)(node0+r)*64 + c]
                         : hT[(size_t)(node0+r)*64 + (c - 64)];
    }
    __syncthreads();
    rd_layer(xs,      w00, b00, ys,  128, o, ng, true);  __syncthreads();
    rd_layer(ys,      w01, b01, zs,  128, o, ng, true);  __syncthreads();
    rd_layer(zs,      w02, b02, os0, 128, o, ng, false); __syncthreads();
    rd_layer(xs + 64, w10, b10, ys,  64,  o, ng, true);  __syncthreads();
    rd_layer(ys,      w11, b11, zs,  128, o, ng, true);  __syncthreads();
    {
        float a0 = b12[o];
        float a1 = a0;
        #pragma unroll 8
        for (int i = 0; i < 128; i += 4){
            float w0 = w12[(size_t)(i+0)*128 + o];
            float w1 = w12[(size_t)(i+1)*128 + o];
            float w2 = w12[(size_t)(i+2)*128 + o];
            float w3 = w12[(size_t)(i+3)*128 + o];
            const float4 x0 = *(const float4*)&zs[ng*128 + i];
            const float4 x1 = *(const float4*)&zs[(ng+2)*128 + i];
            a0 += x0.x*w0 + x0.y*w1 + x0.z*w2 + x0.w*w3;
            a1 += x1.x*w0 + x1.y*w1 + x1.z*w2 + x1.w*w3;
        }
        float s = mS[ng]   * os0[ng*128 + o]     * a0
                + mS[ng+2] * os0[(ng+2)*128 + o] * a1;
        __syncthreads();
        ys[ng*128 + o] = s;
    }
    __syncthreads();
    if (tid < 128)
        partial[(size_t)blockIdx.x*128 + tid] = ys[tid] + ys[128 + tid];
}

// ---------------------------------------------------------------------------
// K5: reduce 12 partials per batch + sigmoid
// ---------------------------------------------------------------------------
__global__ void k_final(const float* __restrict__ partial, float* __restrict__ out)
{
    int idx = blockIdx.x*256 + threadIdx.x;
    if (idx < B_*128){
        int b = idx >> 7, t = idx & 127;
        float s = 0.f;
        #pragma unroll
        for (int c = 0; c < 12; c++) s += partial[(size_t)(b*12 + c)*128 + t];
        out[idx] = 1.0f / (1.0f + expf(-s));
    }
}

// ---------------------------------------------------------------------------
extern "C" void kernel_launch(void* const* d_in, const int* in_sizes, int n_in,
                              void* d_out, int out_size, void* d_ws, size_t ws_size,
                              hipStream_t stream)
{
    (void)in_sizes; (void)n_in; (void)out_size; (void)ws_size;
    const float* g    = (const float*)d_in[0];
    const float* h0   = (const float*)d_in[1];
    const float* e    = (const float*)d_in[2];
    const float* mw0  = (const float*)d_in[3];
    const float* mb0  = (const float*)d_in[4];
    const float* mw1  = (const float*)d_in[5];
    const float* mb1  = (const float*)d_in[6];
    const float* mw2  = (const float*)d_in[7];
    const float* mb2  = (const float*)d_in[8];
    const float* wih  = (const float*)d_in[9];
    const float* whh  = (const float*)d_in[10];
    const float* bih  = (const float*)d_in[11];
    const float* bhh  = (const float*)d_in[12];
    const float* r0w0 = (const float*)d_in[13];
    const float* r0b0 = (const float*)d_in[14];
    const float* r0w1 = (const float*)d_in[15];
    const float* r0b1 = (const float*)d_in[16];
    const float* r0w2 = (const float*)d_in[17];
    const float* r0b2 = (const float*)d_in[18];
    const float* r1w0 = (const float*)d_in[19];
    const float* r1b0 = (const float*)d_in[20];
    const float* r1w1 = (const float*)d_in[21];
    const float* r1b1 = (const float*)d_in[22];
    const float* r1w2 = (const float*)d_in[23];
    const float* r1b2 = (const float*)d_in[24];
    float* out = (float*)d_out;

    float* ws     = (float*)d_ws;
    float* A      = ws;                  // 3*128*64   = 24576
    float* Bm     = A      + 24576;      //              24576
    float* Ab     = Bm     + 24576;      // 3*64       = 192
    float* Bb     = Ab     + 192;        //              192
    float* hfirst = Bb     + 192;        // 768*64     = 49152
    float* hA     = hfirst + 49152;
    float* hB     = hA     + 49152;
    float* mask   = hB     + 49152;      //              768
    float* wihT   = mask   + 768;        // 64*192     = 12288
    float* whhT   = wihT   + 12288;      //              12288
    float* part   = whhT   + 12288;      // 192*128    = 24576
    float* relu2  = part   + 24576;      // 36864*128  = 4718592
    // total ~ 5.0M floats = 19 MiB

    k_pm<<<961, 256, 0, stream>>>(e, mw0, mb0, mw1, mb1, mw2, mb2, h0, wih, whh,
                                  relu2, A, Bm, Ab, Bb, hfirst, mask, wihT, whhT);
    k_layer<<<768, 256, 0, stream>>>(hfirst, hA, relu2, A, Bm, Ab, Bb, g, mask,
                                     wihT, whhT, bih, bhh);
    k_layer<<<768, 256, 0, stream>>>(hA, hB, relu2, A, Bm, Ab, Bb, g, mask,
                                     wihT, whhT, bih, bhh);
    k_layer<<<768, 256, 0, stream>>>(hB, hA, relu2, A, Bm, Ab, Bb, g, mask,
                                     wihT, whhT, bih, bhh);
    k_read<<<192, 256, 0, stream>>>(hfirst, hA, mask,
                                    r0w0, r0b0, r0w1, r0b1, r0w2, r0b2,
                                    r1w0, r1b0, r1w1, r1b1, r1w2, r1b2, part);
    k_final<<<8, 256, 0, stream>>>(part, out);
}

// Round 6
// 206.069 us; speedup vs baseline: 1.0188x; 1.0188x over previous
//
#include <hip/hip_runtime.h>
#include <cmath>

#define B_ 16
#define N_ 48
#define HID_ 64
#define NL_ 128
#define NNODE_ (B_*N_)        // 768
#define NEDGE_ (B_*N_*N_)     // 36864

__device__ __forceinline__ float sigmoidf_(float x){ return 1.0f/(1.0f+expf(-x)); }

// ---------------------------------------------------------------------------
// K_PM: fat kernel. Blocks [0,576): edge-MLP relu2. Blocks [576,961): prep
// (A/B column sums, bias sums, h_first, mask, GRU weight transposes).
// ---------------------------------------------------------------------------
__global__ __launch_bounds__(256) void k_pm(
    const float* __restrict__ ein, const float* __restrict__ w0, const float* __restrict__ b0,
    const float* __restrict__ w1, const float* __restrict__ b1,
    const float* __restrict__ w2, const float* __restrict__ b2,
    const float* __restrict__ h0,
    const float* __restrict__ wih, const float* __restrict__ whh,
    float* __restrict__ relu2,
    float* __restrict__ A, float* __restrict__ Bm,
    float* __restrict__ Ab, float* __restrict__ Bb,
    float* __restrict__ hfirst, float* __restrict__ mask,
    float* __restrict__ wihT, float* __restrict__ whhT)
{
    __shared__ __align__(16) float x1s[64*132];
    int tid = threadIdx.x;

    if (blockIdx.x < 576){
        // ================= edge MLP =================
        int et = tid & 15, ot = tid >> 4;
        int o0 = ot * 8;
        size_t e0 = (size_t)blockIdx.x * 64;

        // ---- layer 1 ----
        float acc[4][8];
        {
            float4 ba = *(const float4*)&b0[o0];
            float4 bb = *(const float4*)&b0[o0 + 4];
            #pragma unroll
            for (int q = 0; q < 4; q++){
                acc[q][0]=ba.x; acc[q][1]=ba.y; acc[q][2]=ba.z; acc[q][3]=ba.w;
                acc[q][4]=bb.x; acc[q][5]=bb.y; acc[q][6]=bb.z; acc[q][7]=bb.w;
            }
        }
        #pragma unroll
        for (int i4 = 0; i4 < 4; i4++){
            float4 ev[4];
            #pragma unroll
            for (int q = 0; q < 4; q++)
                ev[q] = *(const float4*)&ein[(e0 + q*16 + et)*16 + i4*4];
            float wr[4][8];
            #pragma unroll
            for (int d = 0; d < 4; d++){
                *(float4*)&wr[d][0] = *(const float4*)&w0[(i4*4+d)*128 + o0];
                *(float4*)&wr[d][4] = *(const float4*)&w0[(i4*4+d)*128 + o0 + 4];
            }
            #pragma unroll
            for (int q = 0; q < 4; q++){
                #pragma unroll
                for (int r2 = 0; r2 < 8; r2++)
                    acc[q][r2] += ev[q].x*wr[0][r2] + ev[q].y*wr[1][r2]
                                + ev[q].z*wr[2][r2] + ev[q].w*wr[3][r2];
            }
        }
        #pragma unroll
        for (int q = 0; q < 4; q++){
            int e = q*16 + et;
            float4 s0 = make_float4(fmaxf(acc[q][0],0.f), fmaxf(acc[q][1],0.f),
                                    fmaxf(acc[q][2],0.f), fmaxf(acc[q][3],0.f));
            float4 s1 = make_float4(fmaxf(acc[q][4],0.f), fmaxf(acc[q][5],0.f),
                                    fmaxf(acc[q][6],0.f), fmaxf(acc[q][7],0.f));
            *(float4*)&x1s[e*132 + o0]     = s0;
            *(float4*)&x1s[e*132 + o0 + 4] = s1;
        }
        __syncthreads();

        // ---- layer 2 ----
        float a2[4][8];
        {
            float4 ba = *(const float4*)&b1[o0];
            float4 bb = *(const float4*)&b1[o0 + 4];
            #pragma unroll
            for (int q = 0; q < 4; q++){
                a2[q][0]=ba.x; a2[q][1]=ba.y; a2[q][2]=ba.z; a2[q][3]=ba.w;
                a2[q][4]=bb.x; a2[q][5]=bb.y; a2[q][6]=bb.z; a2[q][7]=bb.w;
            }
        }
        for (int i4 = 0; i4 < 32; i4++){
            int i = i4*4;
            float wr[4][8];
            #pragma unroll
            for (int d = 0; d < 4; d++){
                *(float4*)&wr[d][0] = *(const float4*)&w1[(size_t)(i+d)*128 + o0];
                *(float4*)&wr[d][4] = *(const float4*)&w1[(size_t)(i+d)*128 + o0 + 4];
            }
            #pragma unroll
            for (int q = 0; q < 4; q++){
                float4 xv = *(const float4*)&x1s[(q*16 + et)*132 + i];
                #pragma unroll
                for (int r2 = 0; r2 < 8; r2++)
                    a2[q][r2] += xv.x*wr[0][r2] + xv.y*wr[1][r2]
                               + xv.z*wr[2][r2] + xv.w*wr[3][r2];
            }
        }
        #pragma unroll
        for (int q = 0; q < 4; q++){
            size_t e = e0 + q*16 + et;
            float4 s0 = make_float4(fmaxf(a2[q][0],0.f), fmaxf(a2[q][1],0.f),
                                    fmaxf(a2[q][2],0.f), fmaxf(a2[q][3],0.f));
            float4 s1 = make_float4(fmaxf(a2[q][4],0.f), fmaxf(a2[q][5],0.f),
                                    fmaxf(a2[q][6],0.f), fmaxf(a2[q][7],0.f));
            *(float4*)&relu2[e*128 + o0]     = s0;
            *(float4*)&relu2[e*128 + o0 + 4] = s1;
        }
    } else {
        // ================= prep =================
        int idx = (blockIdx.x - 576)*256 + tid;
        if (idx < 24576) {
            int r = idx >> 13, c = (idx >> 6) & 127, m = idx & 63;
            int t = 48 - 16*r;
            const float* src = w2 + c*4096 + m*64;
            float a = 0.f, b = 0.f;
            #pragma unroll
            for (int k4 = 0; k4 < 16; k4++){
                float4 v = *(const float4*)&src[k4*4];
                float s = v.x + v.y + v.z + v.w;
                if (k4*4 < t) a += s; else b += s;
            }
            A[idx] = a; Bm[idx] = b;
        } else if (idx < 24768) {
            int i2 = idx - 24576;
            int r = i2 >> 6, m = i2 & 63;
            int t = 48 - 16*r;
            const float* src = b2 + m*64;
            float a = 0.f, b = 0.f;
            #pragma unroll
            for (int k4 = 0; k4 < 16; k4++){
                float4 v = *(const float4*)&src[k4*4];
                float s = v.x + v.y + v.z + v.w;
                if (k4*4 < t) a += s; else b += s;
            }
            Ab[i2] = a; Bb[i2] = b;
        } else if (idx < 73920) {
            int i3 = idx - 24768;
            int node = i3 >> 6, m = i3 & 63;
            hfirst[i3] = (m < 32) ? h0[node*32 + m] : 0.f;
            if (m == 0) {
                float s = 0.f;
                #pragma unroll
                for (int k = 0; k < 32; k++) s += h0[node*32 + k];
                mask[node] = (s > 0.f) ? 1.f : 0.f;
            }
        } else if (idx < 98496) {
            int i4 = idx - 73920;
            if (i4 < 12288) {
                int k = i4 / 192, col = i4 - k*192;
                wihT[i4] = wih[col*64 + k];
            } else {
                int i5 = i4 - 12288;
                int k = i5 / 192, col = i5 - k*192;
                whhT[i5] = whh[col*64 + k];
            }
        }
    }
}

// ---------------------------------------------------------------------------
// K3: one message-passing layer + GRU. Block per (b,j), 256 threads, 6 phases.
// ---------------------------------------------------------------------------
__global__ __launch_bounds__(256) void k_layer(
    const float* __restrict__ hin, float* __restrict__ hout,
    const float* __restrict__ relu2,
    const float* __restrict__ A, const float* __restrict__ Bm,
    const float* __restrict__ Ab, const float* __restrict__ Bb,
    const float* __restrict__ g, const float* __restrict__ mask,
    const float* __restrict__ wihT, const float* __restrict__ whhT,
    const float* __restrict__ bih, const float* __restrict__ bhh)
{
    int bj = blockIdx.x;
    int b = bj / 48, j = bj - b*48;
    int r = j % 3;
    int p0 = j + j/3;
    int tid = threadIdx.x;
    int base = b*48;
    __shared__ __align__(16) float r2s[48*128];   // 24 KB
    __shared__ float hs[64], wAs[64], wBs[64], Abs[64], Bbs[64];
    __shared__ float pU[2][128], pV[2][128];
    __shared__ float pC[4][64];
    __shared__ float aggs[64], gi[192], gh[192];
    __shared__ float sAB[2];

    // ---- P1: issue all independent loads ----
    {
        const float* src = relu2 + ((size_t)base*48 + j)*128;   // row i at +i*6144
        #pragma unroll
        for (int q2 = 0; q2 < 6; q2++){
            int flat = q2*256 + tid;               // float4 index, 0..1535
            int row = flat >> 5, col = (flat & 31)*4;
            float4 v = *(const float4*)&src[(size_t)row*6144 + col];
            *(float4*)&r2s[row*128 + col] = v;
        }
    }
    if (tid < 64){
        hs[tid] = hin[(size_t)bj*64 + tid];
    } else if (tid < 128){
        int i = tid - 64;                          // lane i of wave 1
        float wa = 0.f, wb = 0.f;
        if (i < 48){
            float gv = g[(size_t)(base+i)*48 + j];
            wa = gv * hin[(size_t)(base+i)*64 + p0];
            wb = gv * hin[(size_t)(base+i)*64 + p0 + 1];
        }
        wAs[i] = wa; wBs[i] = wb;
        float sa = wa, sb = wb;
        #pragma unroll
        for (int d = 32; d >= 1; d >>= 1){
            sa += __shfl_xor(sa, d, 64);
            sb += __shfl_xor(sb, d, 64);
        }
        if (i == 0){ sAB[0] = sa; sAB[1] = sb; }
    } else if (tid < 192){
        Bbs[tid-128] = Bb[r*64 + (tid-128)];
    } else {
        Abs[tid-192] = Ab[r*64 + (tid-192)];
    }
    __syncthreads();

    // ---- P2: U/V partials (all from LDS, conflict-free) ----
    {
        int c = tid & 127, half = tid >> 7;
        float aU = 0.f, aV = 0.f;
        #pragma unroll
        for (int ii = 0; ii < 24; ii++){
            int i = half*24 + ii;
            float v = r2s[i*128 + c];
            aU += wAs[i]*v; aV += wBs[i]*v;
        }
        pU[half][c] = aU; pV[half][c] = aV;
    }
    __syncthreads();

    // ---- P3: agg partials over c ----
    {
        int m = tid & 63, cg = tid >> 6;
        const float* Arp = A  + r*8192 + m;
        const float* Brp = Bm + r*8192 + m;
        float a = 0.f;
        #pragma unroll
        for (int cc = 0; cc < 32; cc++){
            int c = cg*32 + cc;
            float u = pU[0][c] + pU[1][c];
            float v = pV[0][c] + pV[1][c];
            a += u*Arp[(size_t)c*64] + v*Brp[(size_t)c*64];
        }
        pC[cg][m] = a;
    }
    __syncthreads();

    // ---- P4: combine aggs + bias-sum terms ----
    if (tid < 64){
        aggs[tid] = pC[0][tid] + pC[1][tid] + pC[2][tid] + pC[3][tid]
                  + sAB[0]*Abs[tid] + sAB[1]*Bbs[tid];
    }
    __syncthreads();

    // ---- P5: GRU gate matvecs ----
    if (tid < 192){
        float gacc = bih[tid], hacc = bhh[tid];
        #pragma unroll 16
        for (int k = 0; k < 64; k++){
            gacc += aggs[k] * wihT[k*192 + tid];
            hacc += hs[k]   * whhT[k*192 + tid];
        }
        gi[tid] = gacc; gh[tid] = hacc;
    }
    __syncthreads();

    // ---- P6: GRU nonlinearity + masked write ----
    if (tid < 64){
        float rr = sigmoidf_(gi[tid] + gh[tid]);
        float zz = sigmoidf_(gi[64+tid] + gh[64+tid]);
        float nn = tanhf(gi[128+tid] + rr*gh[128+tid]);
        float hnew = (1.f - zz)*nn + zz*hs[tid];
        hout[(size_t)bj*64 + tid] = mask[bj] * hnew;
    }
}

// ---------------------------------------------------------------------------
// K4: readout v3 — weights staged in LDS per layer (stride 129, conflict-free
// scalar reads), activations broadcast. 192 blocks x 256 threads.
// ---------------------------------------------------------------------------
__device__ __forceinline__ void stage_w(const float* __restrict__ W,
                                        float* __restrict__ Ws, int rows, int tid)
{
    for (int f = tid; f < rows*32; f += 256){
        int i = f >> 5, c4 = (f & 31) << 2;
        *(float4*)&Ws[i*129 + c4] = *(const float4*)&W[(size_t)i*128 + c4];
    }
}

__device__ __forceinline__ void lds_layer(const float* __restrict__ Ws,
    const float* __restrict__ xsrc,    // LDS, row stride 132
    const float* __restrict__ bias, float* __restrict__ dst,
    int dim, int o, int ng, bool do_relu)
{
    float a0 = bias[o];
    float a1 = a0;
    #pragma unroll 8
    for (int k = 0; k < dim; k += 4){
        float4 x0 = *(const float4*)&xsrc[ng*132 + k];       // broadcast
        float4 x1 = *(const float4*)&xsrc[(ng+2)*132 + k];
        float w0 = Ws[(k+0)*129 + o];
        float w1 = Ws[(k+1)*129 + o];
        float w2 = Ws[(k+2)*129 + o];
        float w3 = Ws[(k+3)*129 + o];
        a0 += x0.x*w0 + x0.y*w1 + x0.z*w2 + x0.w*w3;
        a1 += x1.x*w0 + x1.y*w1 + x1.z*w2 + x1.w*w3;
    }
    if (do_relu){ a0 = fmaxf(a0, 0.f); a1 = fmaxf(a1, 0.f); }
    dst[ng*132 + o] = a0;
    dst[(ng+2)*132 + o] = a1;
}

__global__ __launch_bounds__(256) void k_read(
    const float* __restrict__ hfirst, const float* __restrict__ hT,
    const float* __restrict__ mask,
    const float* __restrict__ w00, const float* __restrict__ b00,
    const float* __restrict__ w01, const float* __restrict__ b01,
    const float* __restrict__ w02, const float* __restrict__ b02,
    const float* __restrict__ w10, const float* __restrict__ b10,
    const float* __restrict__ w11, const float* __restrict__ b11,
    const float* __restrict__ w12, const float* __restrict__ b12,
    float* __restrict__ partial)
{
    __shared__ __align__(16) float Ws[128*129];   // 66 KB
    __shared__ __align__(16) float xs[4*132], ys[4*132], zs[4*132], os0[4*132];
    __shared__ float mS[4];
    int tid = threadIdx.x;
    int b = blockIdx.x / 12, gg = blockIdx.x - b*12;
    int node0 = b*48 + gg*4;
    int o = tid & 127, ng = tid >> 7;

    if (tid < 4) mS[tid] = mask[node0 + tid];
    for (int i = tid; i < 4*128; i += 256){
        int r = i >> 7, c = i & 127;
        xs[r*132 + c] = (c < 64) ? hfirst[(size_t)(node0+r)*64 + c]
                                 : hT[(size_t)(node0+r)*64 + (c - 64)];
    }
    stage_w(w00, Ws, 128, tid);                       __syncthreads();
    lds_layer(Ws, xs,      b00, ys,  128, o, ng, true);  __syncthreads();
    stage_w(w01, Ws, 128, tid);                       __syncthreads();
    lds_layer(Ws, ys,      b01, zs,  128, o, ng, true);  __syncthreads();
    stage_w(w02, Ws, 128, tid);                       __syncthreads();
    lds_layer(Ws, zs,      b02, os0, 128, o, ng, false); __syncthreads();
    stage_w(w10, Ws, 64, tid);                        __syncthreads();
    lds_layer(Ws, xs + 64, b10, ys,  64,  o, ng, true);  __syncthreads();
    stage_w(w11, Ws, 128, tid);                       __syncthreads();
    lds_layer(Ws, ys,      b11, zs,  128, o, ng, true);  __syncthreads();
    stage_w(w12, Ws, 128, tid);                       __syncthreads();
    // fused last Net1 layer + mask*o0*o1 + node reduction
    {
        float a0 = b12[o];
        float a1 = a0;
        #pragma unroll 8
        for (int k = 0; k < 128; k += 4){
            float4 x0 = *(const float4*)&zs[ng*132 + k];
            float4 x1 = *(const float4*)&zs[(ng+2)*132 + k];
            float w0 = Ws[(k+0)*129 + o];
            float w1 = Ws[(k+1)*129 + o];
            float w2 = Ws[(k+2)*129 + o];
            float w3 = Ws[(k+3)*129 + o];
            a0 += x0.x*w0 + x0.y*w1 + x0.z*w2 + x0.w*w3;
            a1 += x1.x*w0 + x1.y*w1 + x1.z*w2 + x1.w*w3;
        }
        float s = mS[ng]   * os0[ng*132 + o]     * a0
                + mS[ng+2] * os0[(ng+2)*132 + o] * a1;
        __syncthreads();
        ys[ng*132 + o] = s;
    }
    __syncthreads();
    if (tid < 128)
        partial[(size_t)blockIdx.x*128 + tid] = ys[tid] + ys[132 + tid];
}

// ---------------------------------------------------------------------------
// K5: reduce 12 partials per batch + sigmoid
// ---------------------------------------------------------------------------
__global__ void k_final(const float* __restrict__ partial, float* __restrict__ out)
{
    int idx = blockIdx.x*256 + threadIdx.x;
    if (idx < B_*128){
        int b = idx >> 7, t = idx & 127;
        float s = 0.f;
        #pragma unroll
        for (int c = 0; c < 12; c++) s += partial[(size_t)(b*12 + c)*128 + t];
        out[idx] = 1.0f / (1.0f + expf(-s));
    }
}

// ---------------------------------------------------------------------------
extern "C" void kernel_launch(void* const* d_in, const int* in_sizes, int n_in,
                              void* d_out, int out_size, void* d_ws, size_t ws_size,
                              hipStream_t stream)
{
    (void)in_sizes; (void)n_in; (void)out_size; (void)ws_size;
    const float* g    = (const float*)d_in[0];
    const float* h0   = (const float*)d_in[1];
    const float* e    = (const float*)d_in[2];
    const float* mw0  = (const float*)d_in[3];
    const float* mb0  = (const float*)d_in[4];
    const float* mw1  = (const float*)d_in[5];
    const float* mb1  = (const float*)d_in[6];
    const float* mw2  = (const float*)d_in[7];
    const float* mb2  = (const float*)d_in[8];
    const float* wih  = (const float*)d_in[9];
    const float* whh  = (const float*)d_in[10];
    const float* bih  = (const float*)d_in[11];
    const float* bhh  = (const float*)d_in[12];
    const float* r0w0 = (const float*)d_in[13];
    const float* r0b0 = (const float*)d_in[14];
    const float* r0w1 = (const float*)d_in[15];
    const float* r0b1 = (const float*)d_in[16];
    const float* r0w2 = (const float*)d_in[17];
    const float* r0b2 = (const float*)d_in[18];
    const float* r1w0 = (const float*)d_in[19];
    const float* r1b0 = (const float*)d_in[20];
    const float* r1w1 = (const float*)d_in[21];
    const float* r1b1 = (const float*)d_in[22];
    const float* r1w2 = (const float*)d_in[23];
    const float* r1b2 = (const float*)d_in[24];
    float* out = (float*)d_out;

    float* ws     = (float*)d_ws;
    float* A      = ws;                  // 3*128*64   = 24576
    float* Bm     = A      + 24576;      //              24576
    float* Ab     = Bm     + 24576;      // 3*64       = 192
    float* Bb     = Ab     + 192;        //              192
    float* hfirst = Bb     + 192;        // 768*64     = 49152
    float* hA     = hfirst + 49152;
    float* hB     = hA     + 49152;
    float* mask   = hB     + 49152;      //              768
    float* wihT   = mask   + 768;        // 64*192     = 12288
    float* whhT   = wihT   + 12288;      //              12288
    float* part   = whhT   + 12288;      // 192*128    = 24576
    float* relu2  = part   + 24576;      // 36864*128  = 4718592
    // total ~ 5.0M floats = 19 MiB

    k_pm<<<961, 256, 0, stream>>>(e, mw0, mb0, mw1, mb1, mw2, mb2, h0, wih, whh,
                                  relu2, A, Bm, Ab, Bb, hfirst, mask, wihT, whhT);
    k_layer<<<768, 256, 0, stream>>>(hfirst, hA, relu2, A, Bm, Ab, Bb, g, mask,
                                     wihT, whhT, bih, bhh);
    k_layer<<<768, 256, 0, stream>>>(hA, hB, relu2, A, Bm, Ab, Bb, g, mask,
                                     wihT, whhT, bih, bhh);
    k_layer<<<768, 256, 0, stream>>>(hB, hA, relu2, A, Bm, Ab, Bb, g, mask,
                                     wihT, whhT, bih, bhh);
    k_read<<<192, 256, 0, stream>>>(hfirst, hA, mask,
                                    r0w0, r0b0, r0w1, r0b1, r0w2, r0b2,
                                    r1w0, r1b0, r1w1, r1b1, r1w2, r1b2, part);
    k_final<<<8, 256, 0, stream>>>(part, out);
}